// Round 5
// baseline (107.509 us; speedup 1.0000x reference)
//
#include <hip/hip_runtime.h>
#include <math.h>

#define PCK_STRIDE 416
#define N_SAMPLES  32768
#define FFT_M      16384        // full packed complex FFT size
#define HN         8192         // per-half independent complex sub-FFT
#define B_EVENTS   128
#define N_GROUPS   16
#define NT         1024
#define PI_F 3.14159265358979323846f
#define RT2H 0.70710678118654752f   // sqrt(2)/2

// LDS padded mapping (in complex elements): +4 per 32-block. 8-blocks stay
// contiguous and 16B-aligned; float2 accesses are conflict-free (unit stride)
// or <=2-way (q=8 stage), which is free on CDNA4.
#define MAP(i) ((i) + (((i) >> 5) << 2))
#define LDS_H  9216             // MAP(8191)=9211 -> round to 9216 complex

__device__ inline float filt_at(const float* __restrict__ f, int k) {
    if (k >= FFT_M) return 0.0f;
    float c = ((float)k + 0.5f) * (1.0f / 1024.0f) - 0.5f;
    c = fminf(fmaxf(c, 0.0f), 15.0f);
    int i0 = (int)floorf(c);
    int i1 = min(i0 + 1, 15);
    float w = c - (float)i0;
    return f[i0] * (1.0f - w) + f[i1] * w;
}

// ---------------- radix-4 LDS stages, interleaved float2 (b64 ops) ----------------
template<int L>
__device__ inline void r4_dif_stage(float2* z, int tid) {
    constexpr int q = L >> 2;
    constexpr float ang = -6.28318530717958647692f / (float)L;
    #pragma unroll 1
    for (int s = 0; s < (HN / 4) / NT; ++s) {
        int m = tid + s * NT;
        int t = m & (q - 1);
        int i0 = ((m & ~(q - 1)) << 2) | t;
        int ia = MAP(i0), ib = MAP(i0 + q), ic = MAP(i0 + 2 * q), id = MAP(i0 + 3 * q);
        float2 A = z[ia], B = z[ib], C = z[ic], D = z[id];
        float s1, c1; __sincosf(ang * (float)t, &s1, &c1);
        float c2 = c1 * c1 - s1 * s1, s2 = 2.0f * c1 * s1;
        float c3 = c2 * c1 - s2 * s1, s3 = c2 * s1 + s2 * c1;
        float s0r = A.x + C.x, s0i = A.y + C.y;
        float t1r = B.x + D.x, t1i = B.y + D.y;
        float d0r = A.x - C.x, d0i = A.y - C.y;
        float d1r = B.x - D.x, d1i = B.y - D.y;
        z[ia] = make_float2(s0r + t1r, s0i + t1i);
        float er = s0r - t1r, ei = s0i - t1i;
        z[ib] = make_float2(er * c2 - ei * s2, er * s2 + ei * c2);
        float fr = d0r + d1i, fi = d0i - d1r;   // (a-c) - i(b-d)
        z[ic] = make_float2(fr * c1 - fi * s1, fr * s1 + fi * c1);
        float gr = d0r - d1i, gi = d0i + d1r;   // (a-c) + i(b-d)
        z[id] = make_float2(gr * c3 - gi * s3, gr * s3 + gi * c3);
    }
    __syncthreads();
}

template<int L>
__device__ inline void r4_dit_stage(float2* z, int tid) {
    constexpr int q = L >> 2;
    constexpr float ang = 6.28318530717958647692f / (float)L;
    #pragma unroll 1
    for (int s = 0; s < (HN / 4) / NT; ++s) {
        int m = tid + s * NT;
        int t = m & (q - 1);
        int i0 = ((m & ~(q - 1)) << 2) | t;
        int ia = MAP(i0), ib = MAP(i0 + q), ic = MAP(i0 + 2 * q), id = MAP(i0 + 3 * q);
        float2 A = z[ia], B = z[ib], C = z[ic], D = z[id];
        float s1, c1; __sincosf(ang * (float)t, &s1, &c1);
        float c2 = c1 * c1 - s1 * s1, s2 = 2.0f * c1 * s1;
        float tbr = B.x * c2 - B.y * s2, tbi = B.x * s2 + B.y * c2;
        float tdr = D.x * c2 - D.y * s2, tdi = D.x * s2 + D.y * c2;
        float B0r = A.x + tbr, B0i = A.y + tbi;
        float B1r = A.x - tbr, B1i = A.y - tbi;
        float B2r = C.x + tdr, B2i = C.y + tdi;
        float B3r = C.x - tdr, B3i = C.y - tdi;
        float t0r = B2r * c1 - B2i * s1, t0i = B2r * s1 + B2i * c1;
        float t1r = -B3r * s1 - B3i * c1, t1i = B3r * c1 - B3i * s1;  // B3*(i*w1)
        z[ia] = make_float2(B0r + t0r, B0i + t0i);
        z[ib] = make_float2(B1r + t1r, B1i + t1i);
        z[ic] = make_float2(B0r - t0r, B0i - t0i);
        z[id] = make_float2(B1r - t1r, B1i - t1i);
    }
    __syncthreads();
}

// ---------------- K2: per-half 8192-pt middle (all 256 CUs) ----------------
// Halves couple ONLY at first r2 DIF (recomputed per half at load) and last
// r2 DIT (fused into assemble). (k,16384-k) pairs preserve LSB(k) = position
// half, so the untangle/filter stays half-local.
__global__ __launch_bounds__(NT)
void fft_half_kernel(
    const float* __restrict__ noise, const float* __restrict__ packed,
    const float* __restrict__ gamp, float2* __restrict__ hd,
    const float* __restrict__ freqs, float* __restrict__ rW, float* __restrict__ res)
{
    extern __shared__ float smem[];
    float2* z = (float2*)smem;
    float* filt = smem + 2 * LDS_H;
    const int half = blockIdx.x;        // 0: even-k half, 1: odd-k half
    const int b = blockIdx.y;
    const int tid = threadIdx.x;
    const float g = gamp[0];

    // --- load full row + fused r2 DIF, keep this block's half ---
    const float2* nz = (const float2*)(noise + (size_t)b * N_SAMPLES);
    if (half == 0) {
        #pragma unroll 1
        for (int s = 0; s < HN / NT; ++s) {
            int j = tid + s * NT;
            float2 v0 = nz[j];
            float2 v1 = nz[j + HN];
            z[MAP(j)] = make_float2((v0.x + v1.x) * g, (v0.y + v1.y) * g);
        }
    } else {
        #pragma unroll 1
        for (int s = 0; s < HN / NT; ++s) {
            int j = tid + s * NT;
            float2 v0 = nz[j];
            float2 v1 = nz[j + HN];
            float dr = (v0.x - v1.x) * g, di = (v0.y - v1.y) * g;
            float s1, c1; __sincosf((-PI_F / 8192.0f) * (float)j, &s1, &c1);
            z[MAP(j)] = make_float2(dr * c1 - di * s1, dr * s1 + di * c1);
        }
    }
    if (tid >= 64 && tid < 80) filt[tid - 64] = packed[b * PCK_STRIDE + 400 + (tid - 64)];

    // --- fused prep on wave 0 of the half-0 block (shuffle-only) ---
    if (half == 0 && tid < 64) {
        const float* row = packed + b * PCK_STRIDE;
        float n0 = row[tid], n1 = row[tid + 64];
        float fq0 = freqs[tid], fq1 = freqs[tid + 64];
        float mx = fmaxf(n0, n1);
        #pragma unroll
        for (int off = 32; off >= 1; off >>= 1) mx = fmaxf(mx, __shfl_xor(mx, off));
        float e0 = __expf(n0 - mx), e1 = __expf(n1 - mx);
        float den = e0 + e1, num = e0 * fq0 + e1 * fq1;
        #pragma unroll
        for (int off = 32; off >= 1; off >>= 1) {
            den += __shfl_xor(den, off);
            num += __shfl_xor(num, off);
        }
        float ampA = row[256 + tid] * 2.0f - 1.0f;   // frames 0..63
        float ampB = row[320 + tid] * 2.0f - 1.0f;   // frames 64..127
        int h = tid & 7;                              // lanes 8..63 mirror 0..7
        float ha = row[384 + h];
        float hdcy = 0.5f + row[392 + h] * 0.5f;
        const float MIN_F0 = 40.0f / 11025.0f;
        const float F0_SPAN = 3000.0f / 11025.0f - 40.0f / 11025.0f;
        float f0s = num / den;
        float f0 = MIN_F0 + f0s * f0s * 11025.0f * F0_SPAN;
        float r = f0 * (float)(h + 1) * (PI_F / 11025.0f);
        if (r >= PI_F) r = 0.0f;
        if (tid < 8) rW[b * 8 + tid] = r;
        float cur = 0.0f;
        float* rr = res + (b * 8 + h) * 128;
        for (int f = 0; f < 64; ++f) {
            float av = __shfl(ampA, f);
            float c = fmaxf(cur + av * ha, 0.0f);
            if (tid < 8) rr[f] = c;
            cur = c * hdcy;
        }
        for (int f = 0; f < 64; ++f) {
            float av = __shfl(ampB, f);
            float c = fmaxf(cur + av * ha, 0.0f);
            if (tid < 8) rr[64 + f] = c;
            cur = c * hdcy;
        }
    }
    __syncthreads();

    // --- radix-4 DIF stages (8192-pt) ---
    r4_dif_stage<8192>(z, tid);
    r4_dif_stage<2048>(z, tid);
    r4_dif_stage<512>(z, tid);
    r4_dif_stage<128>(z, tid);
    r4_dif_stage<32>(z, tid);

    // --- register radix-8 DIF (half=4,2,1), interleaved float4 LDS I/O ---
    #pragma unroll 1
    for (int s = 0; s < (HN / 8) / NT; ++s) {
        int m = ((HN / 8) / NT) * tid + s;
        float* base = (float*)(z + MAP(8 * m));
        float4 f0 = *(const float4*)(base);        // p0, p1
        float4 f1 = *(const float4*)(base + 4);    // p2, p3
        float4 f2 = *(const float4*)(base + 8);    // p4, p5
        float4 f3 = *(const float4*)(base + 12);   // p6, p7
        // half=4 (pair p_k with p_{k+4})
        float t0r = f0.x + f2.x, t0i = f0.y + f2.y;
        float u0r = f0.x - f2.x, u0i = f0.y - f2.y;
        float t1r = f0.z + f2.z, t1i = f0.w + f2.w;
        float d1r = f0.z - f2.z, d1i = f0.w - f2.w;
        float u1r = RT2H * (d1r + d1i), u1i = RT2H * (d1i - d1r);   // *(c-ci)
        float t2r = f1.x + f3.x, t2i = f1.y + f3.y;
        float d2r = f1.x - f3.x, d2i = f1.y - f3.y;
        float u2r = d2i, u2i = -d2r;                                  // *(-i)
        float t3r = f1.z + f3.z, t3i = f1.w + f3.w;
        float d3r = f1.z - f3.z, d3i = f1.w - f3.w;
        float u3r = RT2H * (d3i - d3r), u3i = -RT2H * (d3r + d3i);  // *(-c-ci)
        // half=2
        float A0r = t0r + t2r, A0i = t0i + t2i;
        float A2r = t0r - t2r, A2i = t0i - t2i;
        float A1r = t1r + t3r, A1i = t1i + t3i;
        float e3r = t1r - t3r, e3i = t1i - t3i;
        float A3r = e3i, A3i = -e3r;                                  // *(-i)
        float B0r = u0r + u2r, B0i = u0i + u2i;
        float B2r = u0r - u2r, B2i = u0i - u2i;
        float B1r = u1r + u3r, B1i = u1i + u3i;
        float f3r = u1r - u3r, f3i = u1i - u3i;
        float B3r = f3i, B3i = -f3r;
        // half=1
        f0.x = A0r + A1r; f0.y = A0i + A1i; f0.z = A0r - A1r; f0.w = A0i - A1i;
        f1.x = A2r + A3r; f1.y = A2i + A3i; f1.z = A2r - A3r; f1.w = A2i - A3i;
        f2.x = B0r + B1r; f2.y = B0i + B1i; f2.z = B0r - B1r; f2.w = B0i - B1i;
        f3.x = B2r + B3r; f3.y = B2i + B3i; f3.z = B2r - B3r; f3.w = B2i - B3i;
        *(float4*)(base) = f0; *(float4*)(base + 4) = f1;
        *(float4*)(base + 8) = f2; *(float4*)(base + 12) = f3;
    }
    __syncthreads();

    // --- pointwise untangle * H * retangle, bitrev domain (half-local) ---
    const float invM = 1.0f / (float)FFT_M;
    #pragma unroll 1
    for (int s = 0; s < (HN / 2) / NT; ++s) {
        int p = (tid + s * NT) << 1;        // even local position
        int jj = (half << 13) | p;          // global bitrev position
        if (jj == 0) {
            float2 z0 = z[MAP(0)];
            float y = 0.5f * filt_at(filt, 0) * (z0.x + z0.y) * invM;
            z[MAP(0)] = make_float2(y, y);
            float H = filt_at(filt, 8192) * invM;   // k=8192 self-pair at brev=1
            float2 z1 = z[MAP(1)];
            z[MAP(1)] = make_float2(z1.x * H, z1.y * H);
        } else {
            int k = (int)(__brev((unsigned)jj) >> 18);     // global k, same parity as half
            int kq = FFT_M - k;
            int pk = MAP(p);
            int pq = MAP((int)(__brev((unsigned)kq) >> 18) & (HN - 1));  // same half
            float2 zk = z[pk];
            float2 zq = z[pq];
            float Er = 0.5f * (zk.x + zq.x), Ei = 0.5f * (zk.y - zq.y);
            float Or = 0.5f * (zk.y + zq.y), Oi = 0.5f * (zq.x - zk.x);
            float th = (float)k * (PI_F / (float)FFT_M);
            float s1, c1; __sincosf(th, &s1, &c1);
            float ts = -s1;
            float tOr = c1 * Or - ts * Oi;
            float tOi = c1 * Oi + ts * Or;
            float Hk = filt_at(filt, k);
            float Hq = filt_at(filt, kq);
            float Ykr = Hk * (Er + tOr), Yki = Hk * (Ei + tOi);
            float Cr  = Hq * (Er - tOr), Ci  = Hq * (Ei - tOi);
            float Ar = 0.5f * (Ykr + Cr), Ai = 0.5f * (Yki + Ci);
            float Br = 0.5f * (Ykr - Cr), Bi = 0.5f * (Yki - Ci);
            z[pk] = make_float2((Ar + ts * Br - c1 * Bi) * invM,
                                (Ai + c1 * Br + ts * Bi) * invM);
            z[pq] = make_float2((Ar + c1 * Bi - ts * Br) * invM,
                                (-Ai + c1 * Br + ts * Bi) * invM);
        }
    }
    __syncthreads();

    // --- register radix-8 DIT (half=1,2,4), interleaved float4 LDS I/O ---
    #pragma unroll 1
    for (int s = 0; s < (HN / 8) / NT; ++s) {
        int m = ((HN / 8) / NT) * tid + s;
        float* base = (float*)(z + MAP(8 * m));
        float4 f0 = *(const float4*)(base);        // p0, p1
        float4 f1 = *(const float4*)(base + 4);    // p2, p3
        float4 f2 = *(const float4*)(base + 8);    // p4, p5
        float4 f3 = *(const float4*)(base + 12);   // p6, p7
        // half=1
        float A0r = f0.x + f0.z, A0i = f0.y + f0.w;
        float A1r = f0.x - f0.z, A1i = f0.y - f0.w;
        float A2r = f1.x + f1.z, A2i = f1.y + f1.w;
        float A3r = f1.x - f1.z, A3i = f1.y - f1.w;
        float B0r = f2.x + f2.z, B0i = f2.y + f2.w;
        float B1r = f2.x - f2.z, B1i = f2.y - f2.w;
        float B2r = f3.x + f3.z, B2i = f3.y + f3.w;
        float B3r = f3.x - f3.z, B3i = f3.y - f3.w;
        // half=2 ; twiddle on odd: *(+i)
        float t0r = A0r + A2r, t0i = A0i + A2i;
        float t2r = A0r - A2r, t2i = A0i - A2i;
        float w3r = -A3i, w3i = A3r;
        float t1r = A1r + w3r, t1i = A1i + w3i;
        float t3r = A1r - w3r, t3i = A1i - w3i;
        float u0r = B0r + B2r, u0i = B0i + B2i;
        float u2r = B0r - B2r, u2i = B0i - B2i;
        float x3r = -B3i, x3i = B3r;
        float u1r = B1r + x3r, u1i = B1i + x3i;
        float u3r = B1r - x3r, u3i = B1i - x3i;
        // half=4 ; twiddles 1, c(1+i), +i, c(-1+i)
        float w1r = RT2H * (u1r - u1i), w1i = RT2H * (u1r + u1i);
        float w2r = -u2i,               w2i = u2r;
        float w5r = RT2H * (-u3r - u3i), w5i = RT2H * (u3r - u3i);
        f0.x = t0r + u0r; f0.y = t0i + u0i;   // p0
        f0.z = t1r + w1r; f0.w = t1i + w1i;   // p1
        f1.x = t2r + w2r; f1.y = t2i + w2i;   // p2
        f1.z = t3r + w5r; f1.w = t3i + w5i;   // p3
        f2.x = t0r - u0r; f2.y = t0i - u0i;   // p4
        f2.z = t1r - w1r; f2.w = t1i - w1i;   // p5
        f3.x = t2r - w2r; f3.y = t2i - w2i;   // p6
        f3.z = t3r - w5r; f3.w = t3i - w5i;   // p7
        *(float4*)(base) = f0; *(float4*)(base + 4) = f1;
        *(float4*)(base + 8) = f2; *(float4*)(base + 12) = f3;
    }
    __syncthreads();

    // --- radix-4 DIT stages (8192-pt) ---
    r4_dit_stage<32>(z, tid);
    r4_dit_stage<128>(z, tid);
    r4_dit_stage<512>(z, tid);
    r4_dit_stage<2048>(z, tid);
    r4_dit_stage<8192>(z, tid);

    // --- store this half (final r2 DIT is fused into assemble) ---
    float2* dst = hd + (size_t)b * FFT_M + (half << 13);
    #pragma unroll 1
    for (int s = 0; s < HN / NT; ++s) {
        int j = tid + s * NT;
        dst[j] = z[MAP(j)];
    }
}

// ---------------- K3: fused final r2 DIT + gate noise + harmonic bank ----------------
// Each thread produces the even/odd sample pair (n0, n0+1): both share the
// same packed slot jl, so U/X loads and the recombine twiddle are read once
// -> hd traffic halves (67 -> 34 MB). Chebyshev U-recurrence per sample.
__global__ __launch_bounds__(256) void assemble_kernel(
    const float* __restrict__ packed, const float* __restrict__ rW,
    const float* __restrict__ res, const float2* __restrict__ hd,
    const float* __restrict__ oamp, float* __restrict__ out)
{
    const int g = blockIdx.y;
    const int chunk = blockIdx.x;           // 512-sample chunk
    const int tid = threadIdx.x;
    const int n0 = chunk * 512 + 2 * tid;
    const int fb = 2 * chunk - 1;           // frames fb..fb+3 cover this chunk

    __shared__ float s_res[8][8][4];
    __shared__ float s_ampf[8][4];
    __shared__ float s_r[8][8];
    {
        int e = tid >> 5, rem = tid & 31, h = rem >> 2, j = rem & 3;
        int f = min(max(fb + j, 0), 127);
        s_res[e][h][j] = res[((g * 8 + e) * 8 + h) * 128 + f];
    }
    if (tid < 32) {
        int e = tid >> 2, j = tid & 3;
        int f = min(max(fb + j, 0), 127);
        s_ampf[e][j] = packed[(g * 8 + e) * PCK_STRIDE + 256 + f] * 2.0f - 1.0f;
    } else if (tid < 96) {
        int u = tid - 32;
        s_r[u >> 3][u & 7] = rW[g * 64 + u];
    }
    __syncthreads();

    // per-sample frame interpolation for n0 and n0+1
    float c0 = fminf(fmaxf(((float)n0 + 0.5f) * (1.0f / 256.0f) - 0.5f, 0.0f), 127.0f);
    float c1v = fminf(fmaxf(((float)n0 + 1.5f) * (1.0f / 256.0f) - 0.5f, 0.0f), 127.0f);
    int i00 = (int)floorf(c0);  float w0 = c0 - (float)i00;  int ja = i00 - fb;
    int i01 = (int)floorf(c1v); float w1 = c1v - (float)i01; int jb = i01 - fb;
    float wm0 = 1.0f - w0, wm1 = 1.0f - w1;
    float osc50 = oamp[0];
    float pn0 = (float)(n0 + 1), pn1 = (float)(n0 + 2);

    // shared recombine twiddle: jglob = n0>>1, uniform half selection per block
    const int jl = ((chunk & 31) << 8) | tid;
    const bool lo = (chunk < 32);
    float sx, cx; __sincosf((PI_F / 8192.0f) * (float)jl, &sx, &cx);

    float acc0 = 0.0f, acc1 = 0.0f;
    #pragma unroll
    for (int e = 0; e < 8; ++e) {
        int b = g * 8 + e;
        const float2* hb = hd + (size_t)b * FFT_M;
        float2 U = hb[jl];
        float2 X = hb[jl + HN];
        float wr2 = X.x * cx - X.y * sx;
        float wi2 = X.x * sx + X.y * cx;
        float nr = lo ? (U.x + wr2) : (U.x - wr2);   // sample n0 (even -> re)
        float ni = lo ? (U.y + wi2) : (U.y - wi2);   // sample n0+1 (odd -> im)
        float av0 = s_ampf[e][ja] * wm0 + s_ampf[e][ja + 1] * w0;
        float av1 = s_ampf[e][jb] * wm1 + s_ampf[e][jb + 1] * w1;
        acc0 += nr * ((av0 >= 0.0f) ? av0 : 0.2f * av0);
        acc1 += ni * ((av1 >= 0.0f) ? av1 : 0.2f * av1);
        float r1 = s_r[e][0];
        float sn0, cn0; __sincosf(pn0 * r1, &sn0, &cn0);
        float sn1, cn1; __sincosf(pn1 * r1, &sn1, &cn1);
        float c20 = 2.0f * cn0, c21 = 2.0f * cn1;
        float sm0 = 0.0f, sh0 = sn0;
        float sm1 = 0.0f, sh1 = sn1;
        #pragma unroll
        for (int h = 0; h < 8; ++h) {
            float rs0 = s_res[e][h][ja] * wm0 + s_res[e][h][ja + 1] * w0;
            float rs1 = s_res[e][h][jb] * wm1 + s_res[e][h][jb + 1] * w1;
            bool nzr = (s_r[e][h] != 0.0f);
            acc0 += rs0 * osc50 * (nzr ? sh0 : 0.0f);
            acc1 += rs1 * osc50 * (nzr ? sh1 : 0.0f);
            float nx0 = c20 * sh0 - sm0; sm0 = sh0; sh0 = nx0;
            float nx1 = c21 * sh1 - sm1; sm1 = sh1; sh1 = nx1;
        }
    }
    *(float2*)(out + (size_t)g * N_SAMPLES + n0) = make_float2(acc0, acc1);
}

extern "C" void kernel_launch(void* const* d_in, const int* in_sizes, int n_in,
                              void* d_out, int out_size, void* d_ws, size_t ws_size,
                              hipStream_t stream) {
    const float* packed = (const float*)d_in[0];
    const float* freqs  = (const float*)d_in[1];
    const float* gamp   = (const float*)d_in[2];
    const float* oamp   = (const float*)d_in[3];
    const float* noise  = (const float*)d_in[4];
    float* out = (float*)d_out;

    float* ws = (float*)d_ws;
    float2* hd = (float2*)ws;                         // 128 * 16384 complex
    float* res = ws + (size_t)B_EVENTS * N_SAMPLES;
    float* rW  = res + B_EVENTS * 8 * 128;

    fft_half_kernel<<<dim3(2, B_EVENTS), NT, (2 * LDS_H + 16) * sizeof(float), stream>>>(
        noise, packed, gamp, hd, freqs, rW, res);
    assemble_kernel<<<dim3(N_SAMPLES / 512, N_GROUPS), 256, 0, stream>>>(
        packed, rW, res, hd, oamp, out);
}

// Round 7
// 106.019 us; speedup vs baseline: 1.0141x; 1.0141x over previous
//
#include <hip/hip_runtime.h>
#include <math.h>

#define PCK_STRIDE 416
#define N_SAMPLES  32768
#define FFT_M      16384        // full packed complex FFT size
#define HN         8192         // per-half independent complex sub-FFT
#define B_EVENTS   128
#define N_GROUPS   16
#define NT         1024
#define PI_F 3.14159265358979323846f
#define RT2H 0.70710678118654752f   // sqrt(2)/2

// LDS padded mapping (in complex elements): +4 per 32-block. 8-blocks stay
// contiguous and 16B-aligned; float2 accesses are conflict-free (unit stride)
// or <=2-way (q=8 stage), which is free on CDNA4.
#define MAP(i) ((i) + (((i) >> 5) << 2))
#define LDS_H  9216             // MAP(8191)=9211 -> round to 9216 complex

__device__ inline float filt_at(const float* __restrict__ f, int k) {
    if (k >= FFT_M) return 0.0f;
    float c = ((float)k + 0.5f) * (1.0f / 1024.0f) - 0.5f;
    c = fminf(fmaxf(c, 0.0f), 15.0f);
    int i0 = (int)floorf(c);
    int i1 = min(i0 + 1, 15);
    float w = c - (float)i0;
    return f[i0] * (1.0f - w) + f[i1] * w;
}

// ---------------- radix-4 LDS stages, interleaved float2 (b64 ops) ----------------
template<int L>
__device__ inline void r4_dif_stage(float2* z, int tid) {
    constexpr int q = L >> 2;
    constexpr float ang = -6.28318530717958647692f / (float)L;
    #pragma unroll 1
    for (int s = 0; s < (HN / 4) / NT; ++s) {
        int m = tid + s * NT;
        int t = m & (q - 1);
        int i0 = ((m & ~(q - 1)) << 2) | t;
        int ia = MAP(i0), ib = MAP(i0 + q), ic = MAP(i0 + 2 * q), id = MAP(i0 + 3 * q);
        float2 A = z[ia], B = z[ib], C = z[ic], D = z[id];
        float s1, c1; __sincosf(ang * (float)t, &s1, &c1);
        float c2 = c1 * c1 - s1 * s1, s2 = 2.0f * c1 * s1;
        float c3 = c2 * c1 - s2 * s1, s3 = c2 * s1 + s2 * c1;
        float s0r = A.x + C.x, s0i = A.y + C.y;
        float t1r = B.x + D.x, t1i = B.y + D.y;
        float d0r = A.x - C.x, d0i = A.y - C.y;
        float d1r = B.x - D.x, d1i = B.y - D.y;
        z[ia] = make_float2(s0r + t1r, s0i + t1i);
        float er = s0r - t1r, ei = s0i - t1i;
        z[ib] = make_float2(er * c2 - ei * s2, er * s2 + ei * c2);
        float fr = d0r + d1i, fi = d0i - d1r;   // (a-c) - i(b-d)
        z[ic] = make_float2(fr * c1 - fi * s1, fr * s1 + fi * c1);
        float gr = d0r - d1i, gi = d0i + d1r;   // (a-c) + i(b-d)
        z[id] = make_float2(gr * c3 - gi * s3, gr * s3 + gi * c3);
    }
    __syncthreads();
}

template<int L>
__device__ inline void r4_dit_stage(float2* z, int tid) {
    constexpr int q = L >> 2;
    constexpr float ang = 6.28318530717958647692f / (float)L;
    #pragma unroll 1
    for (int s = 0; s < (HN / 4) / NT; ++s) {
        int m = tid + s * NT;
        int t = m & (q - 1);
        int i0 = ((m & ~(q - 1)) << 2) | t;
        int ia = MAP(i0), ib = MAP(i0 + q), ic = MAP(i0 + 2 * q), id = MAP(i0 + 3 * q);
        float2 A = z[ia], B = z[ib], C = z[ic], D = z[id];
        float s1, c1; __sincosf(ang * (float)t, &s1, &c1);
        float c2 = c1 * c1 - s1 * s1, s2 = 2.0f * c1 * s1;
        float tbr = B.x * c2 - B.y * s2, tbi = B.x * s2 + B.y * c2;
        float tdr = D.x * c2 - D.y * s2, tdi = D.x * s2 + D.y * c2;
        float B0r = A.x + tbr, B0i = A.y + tbi;
        float B1r = A.x - tbr, B1i = A.y - tbi;
        float B2r = C.x + tdr, B2i = C.y + tdi;
        float B3r = C.x - tdr, B3i = C.y - tdi;
        float t0r = B2r * c1 - B2i * s1, t0i = B2r * s1 + B2i * c1;
        float t1r = -B3r * s1 - B3i * c1, t1i = B3r * c1 - B3i * s1;  // B3*(i*w1)
        z[ia] = make_float2(B0r + t0r, B0i + t0i);
        z[ib] = make_float2(B1r + t1r, B1i + t1i);
        z[ic] = make_float2(B0r - t0r, B0i - t0i);
        z[id] = make_float2(B1r - t1r, B1i - t1i);
    }
    __syncthreads();
}

// ---------------- K2: per-half 8192-pt middle (all 256 CUs) ----------------
// Halves couple ONLY at first r2 DIF (fused into the load, per half) and last
// r2 DIT (fused into assemble). (k,16384-k) pairs preserve LSB(k) = position
// half, so the untangle/filter stays half-local.
// This version additionally fuses the FIRST r4 DIF (L=8192) into the global
// load (registers only, one LDS write round) and the LAST r4 DIT (L=8192)
// into the global store -> 2 fewer LDS rounds + 2 fewer barriers.
__global__ __launch_bounds__(NT)
void fft_half_kernel(
    const float* __restrict__ noise, const float* __restrict__ packed,
    const float* __restrict__ gamp, float2* __restrict__ hd,
    const float* __restrict__ freqs, float* __restrict__ rW, float* __restrict__ res)
{
    extern __shared__ float smem[];
    float2* z = (float2*)smem;
    float* filt = smem + 2 * LDS_H;
    const int half = blockIdx.x;        // 0: even-k half, 1: odd-k half
    const int b = blockIdx.y;
    const int tid = threadIdx.x;
    const float g = gamp[0];

    // --- fused: global load + r2 DIF (keep half) + r4 DIF L=8192, reg-only ---
    const float2* nz = (const float2*)(noise + (size_t)b * N_SAMPLES);
    #pragma unroll 1
    for (int s = 0; s < 2; ++s) {
        int j = tid + s * NT;            // butterfly index in [0,2048)
        float2 a0 = nz[j],        a1 = nz[j + 8192];
        float2 b0 = nz[j + 2048], b1 = nz[j + 10240];
        float2 c0 = nz[j + 4096], c1v = nz[j + 12288];
        float2 d0 = nz[j + 6144], d1 = nz[j + 14336];
        float Arr, Aii, Brr, Bii, Crr, Cii, Drr, Dii;
        if (half == 0) {
            Arr = (a0.x + a1.x) * g; Aii = (a0.y + a1.y) * g;
            Brr = (b0.x + b1.x) * g; Bii = (b0.y + b1.y) * g;
            Crr = (c0.x + c1v.x) * g; Cii = (c0.y + c1v.y) * g;
            Drr = (d0.x + d1.x) * g; Dii = (d0.y + d1.y) * g;
        } else {
            // r2 twiddle w = e^{-i pi j/8192}; offsets +2048,+4096,+6144 are
            // exact rotations by e^{-i pi/4}, e^{-i pi/2}, e^{-i 3pi/4}.
            float sw, cw; __sincosf((-PI_F / 8192.0f) * (float)j, &sw, &cw);
            float cwB = RT2H * (cw + sw), swB = RT2H * (sw - cw);   // * e^{-i pi/4}
            float cwC = sw,               swC = -cw;                 // * e^{-i pi/2}
            float cwD = RT2H * (sw - cw), swD = -RT2H * (cw + sw);  // * e^{-i 3pi/4}
            float dr, di;
            dr = (a0.x - a1.x) * g; di = (a0.y - a1.y) * g;
            Arr = dr * cw - di * sw;  Aii = dr * sw + di * cw;
            dr = (b0.x - b1.x) * g; di = (b0.y - b1.y) * g;
            Brr = dr * cwB - di * swB; Bii = dr * swB + di * cwB;
            dr = (c0.x - c1v.x) * g; di = (c0.y - c1v.y) * g;
            Crr = dr * cwC - di * swC; Cii = dr * swC + di * cwC;
            dr = (d0.x - d1.x) * g; di = (d0.y - d1.y) * g;
            Drr = dr * cwD - di * swD; Dii = dr * swD + di * cwD;
        }
        // r4 DIF butterfly, L=8192, q=2048, t=j
        float s1, c1; __sincosf((-6.28318530717958647692f / 8192.0f) * (float)j, &s1, &c1);
        float c2 = c1 * c1 - s1 * s1, s2 = 2.0f * c1 * s1;
        float c3 = c2 * c1 - s2 * s1, s3 = c2 * s1 + s2 * c1;
        float s0r = Arr + Crr, s0i = Aii + Cii;
        float t1r = Brr + Drr, t1i = Bii + Dii;
        float d0r = Arr - Crr, d0i = Aii - Cii;
        float d1r = Brr - Drr, d1i = Bii - Dii;
        z[MAP(j)] = make_float2(s0r + t1r, s0i + t1i);
        float er = s0r - t1r, ei = s0i - t1i;
        z[MAP(j + 2048)] = make_float2(er * c2 - ei * s2, er * s2 + ei * c2);
        float fr = d0r + d1i, fi = d0i - d1r;
        z[MAP(j + 4096)] = make_float2(fr * c1 - fi * s1, fr * s1 + fi * c1);
        float gr = d0r - d1i, gi = d0i + d1r;
        z[MAP(j + 6144)] = make_float2(gr * c3 - gi * s3, gr * s3 + gi * c3);
    }
    if (tid >= 64 && tid < 80) filt[tid - 64] = packed[b * PCK_STRIDE + 400 + (tid - 64)];

    // --- fused prep on wave 0 of the half-0 block (shuffle-only) ---
    if (half == 0 && tid < 64) {
        const float* row = packed + b * PCK_STRIDE;
        float n0 = row[tid], n1 = row[tid + 64];
        float fq0 = freqs[tid], fq1 = freqs[tid + 64];
        float mx = fmaxf(n0, n1);
        #pragma unroll
        for (int off = 32; off >= 1; off >>= 1) mx = fmaxf(mx, __shfl_xor(mx, off));
        float e0 = __expf(n0 - mx), e1 = __expf(n1 - mx);
        float den = e0 + e1, num = e0 * fq0 + e1 * fq1;
        #pragma unroll
        for (int off = 32; off >= 1; off >>= 1) {
            den += __shfl_xor(den, off);
            num += __shfl_xor(num, off);
        }
        float ampA = row[256 + tid] * 2.0f - 1.0f;   // frames 0..63
        float ampB = row[320 + tid] * 2.0f - 1.0f;   // frames 64..127
        int h = tid & 7;                              // lanes 8..63 mirror 0..7
        float ha = row[384 + h];
        float hdcy = 0.5f + row[392 + h] * 0.5f;
        const float MIN_F0 = 40.0f / 11025.0f;
        const float F0_SPAN = 3000.0f / 11025.0f - 40.0f / 11025.0f;
        float f0s = num / den;
        float f0 = MIN_F0 + f0s * f0s * 11025.0f * F0_SPAN;
        float r = f0 * (float)(h + 1) * (PI_F / 11025.0f);
        if (r >= PI_F) r = 0.0f;
        if (tid < 8) rW[b * 8 + tid] = r;
        float cur = 0.0f;
        float* rr = res + (b * 8 + h) * 128;
        for (int f = 0; f < 64; ++f) {
            float av = __shfl(ampA, f);
            float c = fmaxf(cur + av * ha, 0.0f);
            if (tid < 8) rr[f] = c;
            cur = c * hdcy;
        }
        for (int f = 0; f < 64; ++f) {
            float av = __shfl(ampB, f);
            float c = fmaxf(cur + av * ha, 0.0f);
            if (tid < 8) rr[64 + f] = c;
            cur = c * hdcy;
        }
    }
    __syncthreads();

    // --- radix-4 DIF stages (L=8192 fused into load above) ---
    r4_dif_stage<2048>(z, tid);
    r4_dif_stage<512>(z, tid);
    r4_dif_stage<128>(z, tid);
    r4_dif_stage<32>(z, tid);

    // --- register radix-8 DIF (half=4,2,1), interleaved float4 LDS I/O ---
    #pragma unroll 1
    for (int s = 0; s < (HN / 8) / NT; ++s) {
        int m = ((HN / 8) / NT) * tid + s;
        float* base = (float*)(z + MAP(8 * m));
        float4 f0 = *(const float4*)(base);        // p0, p1
        float4 f1 = *(const float4*)(base + 4);    // p2, p3
        float4 f2 = *(const float4*)(base + 8);    // p4, p5
        float4 f3 = *(const float4*)(base + 12);   // p6, p7
        // half=4 (pair p_k with p_{k+4})
        float t0r = f0.x + f2.x, t0i = f0.y + f2.y;
        float u0r = f0.x - f2.x, u0i = f0.y - f2.y;
        float t1r = f0.z + f2.z, t1i = f0.w + f2.w;
        float d1r = f0.z - f2.z, d1i = f0.w - f2.w;
        float u1r = RT2H * (d1r + d1i), u1i = RT2H * (d1i - d1r);   // *(c-ci)
        float t2r = f1.x + f3.x, t2i = f1.y + f3.y;
        float d2r = f1.x - f3.x, d2i = f1.y - f3.y;
        float u2r = d2i, u2i = -d2r;                                  // *(-i)
        float t3r = f1.z + f3.z, t3i = f1.w + f3.w;
        float d3r = f1.z - f3.z, d3i = f1.w - f3.w;
        float u3r = RT2H * (d3i - d3r), u3i = -RT2H * (d3r + d3i);  // *(-c-ci)
        // half=2
        float A0r = t0r + t2r, A0i = t0i + t2i;
        float A2r = t0r - t2r, A2i = t0i - t2i;
        float A1r = t1r + t3r, A1i = t1i + t3i;
        float e3r = t1r - t3r, e3i = t1i - t3i;
        float A3r = e3i, A3i = -e3r;                                  // *(-i)
        float B0r = u0r + u2r, B0i = u0i + u2i;
        float B2r = u0r - u2r, B2i = u0i - u2i;
        float B1r = u1r + u3r, B1i = u1i + u3i;
        float f3r = u1r - u3r, f3i = u1i - u3i;
        float B3r = f3i, B3i = -f3r;
        // half=1
        f0.x = A0r + A1r; f0.y = A0i + A1i; f0.z = A0r - A1r; f0.w = A0i - A1i;
        f1.x = A2r + A3r; f1.y = A2i + A3i; f1.z = A2r - A3r; f1.w = A2i - A3i;
        f2.x = B0r + B1r; f2.y = B0i + B1i; f2.z = B0r - B1r; f2.w = B0i - B1i;
        f3.x = B2r + B3r; f3.y = B2i + B3i; f3.z = B2r - B3r; f3.w = B2i - B3i;
        *(float4*)(base) = f0; *(float4*)(base + 4) = f1;
        *(float4*)(base + 8) = f2; *(float4*)(base + 12) = f3;
    }
    __syncthreads();

    // --- pointwise untangle * H * retangle, bitrev domain (half-local) ---
    const float invM = 1.0f / (float)FFT_M;
    #pragma unroll 1
    for (int s = 0; s < (HN / 2) / NT; ++s) {
        int p = (tid + s * NT) << 1;        // even local position
        int jj = (half << 13) | p;          // global bitrev position
        if (jj == 0) {
            float2 z0 = z[MAP(0)];
            float y = 0.5f * filt_at(filt, 0) * (z0.x + z0.y) * invM;
            z[MAP(0)] = make_float2(y, y);
            float H = filt_at(filt, 8192) * invM;   // k=8192 self-pair at brev=1
            float2 z1 = z[MAP(1)];
            z[MAP(1)] = make_float2(z1.x * H, z1.y * H);
        } else {
            int k = (int)(__brev((unsigned)jj) >> 18);     // global k, same parity as half
            int kq = FFT_M - k;
            int pk = MAP(p);
            int pq = MAP((int)(__brev((unsigned)kq) >> 18) & (HN - 1));  // same half
            float2 zk = z[pk];
            float2 zq = z[pq];
            float Er = 0.5f * (zk.x + zq.x), Ei = 0.5f * (zk.y - zq.y);
            float Or = 0.5f * (zk.y + zq.y), Oi = 0.5f * (zq.x - zk.x);
            float th = (float)k * (PI_F / (float)FFT_M);
            float s1, c1; __sincosf(th, &s1, &c1);
            float ts = -s1;
            float tOr = c1 * Or - ts * Oi;
            float tOi = c1 * Oi + ts * Or;
            float Hk = filt_at(filt, k);
            float Hq = filt_at(filt, kq);
            float Ykr = Hk * (Er + tOr), Yki = Hk * (Ei + tOi);
            float Cr  = Hq * (Er - tOr), Ci  = Hq * (Ei - tOi);
            float Ar = 0.5f * (Ykr + Cr), Ai = 0.5f * (Yki + Ci);
            float Br = 0.5f * (Ykr - Cr), Bi = 0.5f * (Yki - Ci);
            z[pk] = make_float2((Ar + ts * Br - c1 * Bi) * invM,
                                (Ai + c1 * Br + ts * Bi) * invM);
            z[pq] = make_float2((Ar + c1 * Bi - ts * Br) * invM,
                                (-Ai + c1 * Br + ts * Bi) * invM);
        }
    }
    __syncthreads();

    // --- register radix-8 DIT (half=1,2,4), interleaved float4 LDS I/O ---
    #pragma unroll 1
    for (int s = 0; s < (HN / 8) / NT; ++s) {
        int m = ((HN / 8) / NT) * tid + s;
        float* base = (float*)(z + MAP(8 * m));
        float4 f0 = *(const float4*)(base);        // p0, p1
        float4 f1 = *(const float4*)(base + 4);    // p2, p3
        float4 f2 = *(const float4*)(base + 8);    // p4, p5
        float4 f3 = *(const float4*)(base + 12);   // p6, p7
        // half=1
        float A0r = f0.x + f0.z, A0i = f0.y + f0.w;
        float A1r = f0.x - f0.z, A1i = f0.y - f0.w;
        float A2r = f1.x + f1.z, A2i = f1.y + f1.w;
        float A3r = f1.x - f1.z, A3i = f1.y - f1.w;
        float B0r = f2.x + f2.z, B0i = f2.y + f2.w;
        float B1r = f2.x - f2.z, B1i = f2.y - f2.w;
        float B2r = f3.x + f3.z, B2i = f3.y + f3.w;
        float B3r = f3.x - f3.z, B3i = f3.y - f3.w;
        // half=2 ; twiddle on odd: *(+i)
        float t0r = A0r + A2r, t0i = A0i + A2i;
        float t2r = A0r - A2r, t2i = A0i - A2i;
        float w3r = -A3i, w3i = A3r;
        float t1r = A1r + w3r, t1i = A1i + w3i;
        float t3r = A1r - w3r, t3i = A1i - w3i;
        float u0r = B0r + B2r, u0i = B0i + B2i;
        float u2r = B0r - B2r, u2i = B0i - B2i;
        float x3r = -B3i, x3i = B3r;
        float u1r = B1r + x3r, u1i = B1i + x3i;
        float u3r = B1r - x3r, u3i = B1i - x3i;
        // half=4 ; twiddles 1, c(1+i), +i, c(-1+i)
        float w1r = RT2H * (u1r - u1i), w1i = RT2H * (u1r + u1i);
        float w2r = -u2i,               w2i = u2r;
        float w5r = RT2H * (-u3r - u3i), w5i = RT2H * (u3r - u3i);
        f0.x = t0r + u0r; f0.y = t0i + u0i;   // p0
        f0.z = t1r + w1r; f0.w = t1i + w1i;   // p1
        f1.x = t2r + w2r; f1.y = t2i + w2i;   // p2
        f1.z = t3r + w5r; f1.w = t3i + w5i;   // p3
        f2.x = t0r - u0r; f2.y = t0i - u0i;   // p4
        f2.z = t1r - w1r; f2.w = t1i - w1i;   // p5
        f3.x = t2r - w2r; f3.y = t2i - w2i;   // p6
        f3.z = t3r - w5r; f3.w = t3i - w5i;   // p7
        *(float4*)(base) = f0; *(float4*)(base + 4) = f1;
        *(float4*)(base + 8) = f2; *(float4*)(base + 12) = f3;
    }
    __syncthreads();

    // --- radix-4 DIT stages (L=8192 fused into store below) ---
    r4_dit_stage<32>(z, tid);
    r4_dit_stage<128>(z, tid);
    r4_dit_stage<512>(z, tid);
    r4_dit_stage<2048>(z, tid);

    // --- fused: last r4 DIT (L=8192, q=2048) + global store (natural order) ---
    float2* dst = hd + (size_t)b * FFT_M + (half << 13);
    #pragma unroll 1
    for (int s = 0; s < 2; ++s) {
        int m = tid + s * NT;              // t = m, i0 = m
        float2 A = z[MAP(m)], B = z[MAP(m + 2048)];
        float2 C = z[MAP(m + 4096)], D = z[MAP(m + 6144)];
        float s1, c1; __sincosf((6.28318530717958647692f / 8192.0f) * (float)m, &s1, &c1);
        float c2 = c1 * c1 - s1 * s1, s2 = 2.0f * c1 * s1;
        float tbr = B.x * c2 - B.y * s2, tbi = B.x * s2 + B.y * c2;
        float tdr = D.x * c2 - D.y * s2, tdi = D.x * s2 + D.y * c2;
        float B0r = A.x + tbr, B0i = A.y + tbi;
        float B1r = A.x - tbr, B1i = A.y - tbi;
        float B2r = C.x + tdr, B2i = C.y + tdi;
        float B3r = C.x - tdr, B3i = C.y - tdi;
        float t0r = B2r * c1 - B2i * s1, t0i = B2r * s1 + B2i * c1;
        float t1r = -B3r * s1 - B3i * c1, t1i = B3r * c1 - B3i * s1;  // B3*(i*w1)
        dst[m]        = make_float2(B0r + t0r, B0i + t0i);
        dst[m + 2048] = make_float2(B1r + t1r, B1i + t1i);
        dst[m + 4096] = make_float2(B0r - t0r, B0i - t0i);
        dst[m + 6144] = make_float2(B1r - t1r, B1i - t1i);
    }
}

// ---------------- K3: fused final r2 DIT + gate noise + harmonic bank ----------------
// Each thread produces the even/odd sample pair (n0, n0+1): both share the
// same packed slot jl, so U/X loads and the recombine twiddle are read once
// -> hd traffic halves (67 -> 34 MB). Chebyshev U-recurrence per sample.
__global__ __launch_bounds__(256) void assemble_kernel(
    const float* __restrict__ packed, const float* __restrict__ rW,
    const float* __restrict__ res, const float2* __restrict__ hd,
    const float* __restrict__ oamp, float* __restrict__ out)
{
    const int g = blockIdx.y;
    const int chunk = blockIdx.x;           // 512-sample chunk
    const int tid = threadIdx.x;
    const int n0 = chunk * 512 + 2 * tid;
    const int fb = 2 * chunk - 1;           // frames fb..fb+3 cover this chunk

    __shared__ float s_res[8][8][4];
    __shared__ float s_ampf[8][4];
    __shared__ float s_r[8][8];
    {
        int e = tid >> 5, rem = tid & 31, h = rem >> 2, j = rem & 3;
        int f = min(max(fb + j, 0), 127);
        s_res[e][h][j] = res[((g * 8 + e) * 8 + h) * 128 + f];
    }
    if (tid < 32) {
        int e = tid >> 2, j = tid & 3;
        int f = min(max(fb + j, 0), 127);
        s_ampf[e][j] = packed[(g * 8 + e) * PCK_STRIDE + 256 + f] * 2.0f - 1.0f;
    } else if (tid < 96) {
        int u = tid - 32;
        s_r[u >> 3][u & 7] = rW[g * 64 + u];
    }
    __syncthreads();

    // per-sample frame interpolation for n0 and n0+1
    float c0 = fminf(fmaxf(((float)n0 + 0.5f) * (1.0f / 256.0f) - 0.5f, 0.0f), 127.0f);
    float c1v = fminf(fmaxf(((float)n0 + 1.5f) * (1.0f / 256.0f) - 0.5f, 0.0f), 127.0f);
    int i00 = (int)floorf(c0);  float w0 = c0 - (float)i00;  int ja = i00 - fb;
    int i01 = (int)floorf(c1v); float w1 = c1v - (float)i01; int jb = i01 - fb;
    float wm0 = 1.0f - w0, wm1 = 1.0f - w1;
    float osc50 = oamp[0];
    float pn0 = (float)(n0 + 1), pn1 = (float)(n0 + 2);

    // shared recombine twiddle: jglob = n0>>1, uniform half selection per block
    const int jl = ((chunk & 31) << 8) | tid;
    const bool lo = (chunk < 32);
    float sx, cx; __sincosf((PI_F / 8192.0f) * (float)jl, &sx, &cx);

    float acc0 = 0.0f, acc1 = 0.0f;
    #pragma unroll
    for (int e = 0; e < 8; ++e) {
        int b = g * 8 + e;
        const float2* hb = hd + (size_t)b * FFT_M;
        float2 U = hb[jl];
        float2 X = hb[jl + HN];
        float wr2 = X.x * cx - X.y * sx;
        float wi2 = X.x * sx + X.y * cx;
        float nr = lo ? (U.x + wr2) : (U.x - wr2);   // sample n0 (even -> re)
        float ni = lo ? (U.y + wi2) : (U.y - wi2);   // sample n0+1 (odd -> im)
        float av0 = s_ampf[e][ja] * wm0 + s_ampf[e][ja + 1] * w0;
        float av1 = s_ampf[e][jb] * wm1 + s_ampf[e][jb + 1] * w1;
        acc0 += nr * ((av0 >= 0.0f) ? av0 : 0.2f * av0);
        acc1 += ni * ((av1 >= 0.0f) ? av1 : 0.2f * av1);
        float r1 = s_r[e][0];
        float sn0, cn0; __sincosf(pn0 * r1, &sn0, &cn0);
        float sn1, cn1; __sincosf(pn1 * r1, &sn1, &cn1);
        float c20 = 2.0f * cn0, c21 = 2.0f * cn1;
        float sm0 = 0.0f, sh0 = sn0;
        float sm1 = 0.0f, sh1 = sn1;
        #pragma unroll
        for (int h = 0; h < 8; ++h) {
            float rs0 = s_res[e][h][ja] * wm0 + s_res[e][h][ja + 1] * w0;
            float rs1 = s_res[e][h][jb] * wm1 + s_res[e][h][jb + 1] * w1;
            bool nzr = (s_r[e][h] != 0.0f);
            acc0 += rs0 * osc50 * (nzr ? sh0 : 0.0f);
            acc1 += rs1 * osc50 * (nzr ? sh1 : 0.0f);
            float nx0 = c20 * sh0 - sm0; sm0 = sh0; sh0 = nx0;
            float nx1 = c21 * sh1 - sm1; sm1 = sh1; sh1 = nx1;
        }
    }
    *(float2*)(out + (size_t)g * N_SAMPLES + n0) = make_float2(acc0, acc1);
}

extern "C" void kernel_launch(void* const* d_in, const int* in_sizes, int n_in,
                              void* d_out, int out_size, void* d_ws, size_t ws_size,
                              hipStream_t stream) {
    const float* packed = (const float*)d_in[0];
    const float* freqs  = (const float*)d_in[1];
    const float* gamp   = (const float*)d_in[2];
    const float* oamp   = (const float*)d_in[3];
    const float* noise  = (const float*)d_in[4];
    float* out = (float*)d_out;

    float* ws = (float*)d_ws;
    float2* hd = (float2*)ws;                         // 128 * 16384 complex
    float* res = ws + (size_t)B_EVENTS * N_SAMPLES;
    float* rW  = res + B_EVENTS * 8 * 128;

    fft_half_kernel<<<dim3(2, B_EVENTS), NT, (2 * LDS_H + 16) * sizeof(float), stream>>>(
        noise, packed, gamp, hd, freqs, rW, res);
    assemble_kernel<<<dim3(N_SAMPLES / 512, N_GROUPS), 256, 0, stream>>>(
        packed, rW, res, hd, oamp, out);
}